// Round 9
// baseline (230.184 us; speedup 1.0000x reference)
//
#include <hip/hip_runtime.h>

// Problem constants (fixed by the reference setup_inputs()).
#define N_NODES 100000
#define NPAD    100032  // N rounded up to 64; h1s/h2s have zero rows N..NPAD-1
#define N_EDGES 1600000
#define IN_CH   128
#define HID_CH  64
#define OUT_CH  40
#define NBKT    196     // ceil(100000/512) buckets of 512 nodes
#define EPB     4096    // edges per k_bin block
#define CAP     9216    // ebuf bucket capacity (mean 8186, sigma ~90 -> 11 sigma)
#define CAPC    10752   // csr bucket capacity incl. per-node pad-to-8 (mean ~9978)

using bf16x8 = __attribute__((ext_vector_type(8))) short;
using f32x4  = __attribute__((ext_vector_type(4))) float;

// bf16 helpers (tables are bf16; all accumulation fp32)
__device__ __forceinline__ float bf2f(unsigned short u) {
    union { unsigned int i; float f; } c; c.i = ((unsigned int)u) << 16; return c.f;
}
__device__ __forceinline__ unsigned short f2bf(float f) {
    union { float f; unsigned int i; } c; c.f = f;
    unsigned int r = c.i + 0x7FFFu + ((c.i >> 16) & 1u);  // RNE
    return (unsigned short)(r >> 16);
}
__device__ __forceinline__ float4 bf2f4(ushort4 u) {
    return make_float4(bf2f(u.x), bf2f(u.y), bf2f(u.z), bf2f(u.w));
}

// ---------------------------------------------------------------------------
// bin edges into fixed-base bucket regions; gcur holds per-bucket DELTAS
// (zeroed by hipMemsetAsync). packed word: src | ((dst&511)<<17)
// ---------------------------------------------------------------------------
__global__ void k_bin(const int* __restrict__ ei, int* __restrict__ gcur,
                      int* __restrict__ ebuf) {
    __shared__ int hist[NBKT];
    __shared__ int lcur[NBKT];
    int tid = threadIdx.x;
    int base = blockIdx.x * EPB;
    int nloc = N_EDGES - base;
    if (nloc > EPB) nloc = EPB;
    int n4 = nloc >> 2;   // nloc is 4096 or 2560, both %4==0
    const int4* S4 = (const int4*)(ei + base);
    const int4* D4 = (const int4*)(ei + N_EDGES + base);

    if (tid < NBKT) { hist[tid] = 0; }
    __syncthreads();
    for (int i = tid; i < n4; i += 256) {
        int4 d = D4[i];
        atomicAdd(&hist[d.x >> 9], 1);
        atomicAdd(&hist[d.y >> 9], 1);
        atomicAdd(&hist[d.z >> 9], 1);
        atomicAdd(&hist[d.w >> 9], 1);
    }
    __syncthreads();
    if (tid < NBKT) {
        int h = hist[tid];
        lcur[tid] = h ? (tid * CAP + atomicAdd(&gcur[tid], h)) : 0;
    }
    __syncthreads();
    for (int i = tid; i < n4; i += 256) {
        int4 s = S4[i];
        int4 d = D4[i];
        int p;
        p = atomicAdd(&lcur[d.x >> 9], 1); ebuf[p] = s.x | ((d.x & 511) << 17);
        p = atomicAdd(&lcur[d.y >> 9], 1); ebuf[p] = s.y | ((d.y & 511) << 17);
        p = atomicAdd(&lcur[d.z >> 9], 1); ebuf[p] = s.z | ((d.z & 511) << 17);
        p = atomicAdd(&lcur[d.w >> 9], 1); ebuf[p] = s.w | ((d.w & 511) << 17);
    }
}

// ---------------------------------------------------------------------------
// per-bucket (512 nodes, 512 threads): count, scan PADDED counts (to mult.
// of 8), emit row_start/row_end/dinv, place edges, fill pad slots with
// src = N_NODES (h1s/h2s row N_NODES is all-zero -> pad gathers are no-ops,
// permanently cache-hot). Removes every serial remainder loop downstream.
// ---------------------------------------------------------------------------
__global__ void k_node(const int* __restrict__ gcur, const int* __restrict__ ebuf,
                       int* __restrict__ row_start, int* __restrict__ row_end,
                       int* __restrict__ csr_src, float* __restrict__ dinv) {
    __shared__ int cnt[512];
    __shared__ int s[512];
    int tid = threadIdx.x;
    int b = blockIdx.x;
    int node0 = b << 9;
    int lo = b * CAP;          // ebuf region
    int lo2 = b * CAPC;        // csr region (padded)
    int hi = lo + gcur[b];
    int n = hi - lo, n4 = n >> 2;
    const int4* E4 = (const int4*)(ebuf + lo);   // 16B aligned (CAP%4==0)

    cnt[tid] = 0;
    __syncthreads();
    for (int i = tid; i < n4; i += 512) {
        int4 w = E4[i];
        atomicAdd(&cnt[(unsigned)w.x >> 17], 1);
        atomicAdd(&cnt[(unsigned)w.y >> 17], 1);
        atomicAdd(&cnt[(unsigned)w.z >> 17], 1);
        atomicAdd(&cnt[(unsigned)w.w >> 17], 1);
    }
    for (int e = lo + (n4 << 2) + tid; e < hi; e += 512)
        atomicAdd(&cnt[(unsigned)ebuf[e] >> 17], 1);
    __syncthreads();
    int c = cnt[tid];
    int cp = (c + 7) & ~7;     // padded to multiple of 8
    s[tid] = cp;
    __syncthreads();
#pragma unroll
    for (int off = 1; off < 512; off <<= 1) {
        int tv = (tid >= off) ? s[tid - off] : 0;
        __syncthreads();
        s[tid] += tv;
        __syncthreads();
    }
    int nodestart = lo2 + s[tid] - cp;
    int node = node0 + tid;
    if (node < N_NODES) {
        row_start[node] = nodestart;
        row_end[node]   = nodestart + c;
        dinv[node] = rsqrtf(1.0f + (float)c);
    }
    __syncthreads();
    cnt[tid] = nodestart;  // reuse as cursor
    __syncthreads();
    for (int i = tid; i < n4; i += 512) {
        int4 w = E4[i];
        int p;
        p = atomicAdd(&cnt[(unsigned)w.x >> 17], 1); csr_src[p] = w.x & 0x1FFFF;
        p = atomicAdd(&cnt[(unsigned)w.y >> 17], 1); csr_src[p] = w.y & 0x1FFFF;
        p = atomicAdd(&cnt[(unsigned)w.z >> 17], 1); csr_src[p] = w.z & 0x1FFFF;
        p = atomicAdd(&cnt[(unsigned)w.w >> 17], 1); csr_src[p] = w.w & 0x1FFFF;
    }
    for (int e = lo + (n4 << 2) + tid; e < hi; e += 512) {
        int w = ebuf[e];
        int p = atomicAdd(&cnt[(unsigned)w >> 17], 1);
        csr_src[p] = w & 0x1FFFF;
    }
    // pad fill: disjoint from placement range, no barrier needed
    for (int p = nodestart + c; p < nodestart + cp; ++p)
        csr_src[p] = N_NODES;
}

// ---------------------------------------------------------------------------
// GEMM1 (MFMA bf16): h1s[N,64] = bf16((x @ W1) * dinv[row]);
// rows N..NPAD-1 written as ZEROS (pad row for gather no-ops).
// A-fragment loaded DIRECTLY from x (8 contiguous floats = float4 x2) —
// no LDS staging for A; only W1^T staged.
// ---------------------------------------------------------------------------
__global__ __launch_bounds__(256, 4)
void k_gemm1(const float* __restrict__ x, const float* __restrict__ W1,
             const float* __restrict__ dinv, unsigned short* __restrict__ h1s) {
    __shared__ unsigned short Bl[64 * 136];  // 17 KB
    __shared__ float dl[64];
    int tid = threadIdx.x;
    long long node0 = (long long)blockIdx.x * 64;

    // stage B with transpose: W1[k][n] fp32 -> Bl[n*136 + k] bf16
    for (int i = tid; i < 128 * 64; i += 256) {
        int k = i >> 6, nn = i & 63;
        Bl[nn * 136 + k] = f2bf(W1[i]);
    }
    if (tid < 64) {
        long long gr = node0 + tid;
        dl[tid] = dinv[gr < N_NODES ? gr : N_NODES - 1];
    }
    __syncthreads();

    int lane = tid & 63, wave = tid >> 6;
    int quad = lane >> 4, l16 = lane & 15;
    int arow = wave * 16 + l16;
    long long ga = node0 + arow;
    if (ga >= N_NODES) ga = N_NODES - 1;   // clamp (pad rows written zero below)
    const float* xr = x + ga * IN_CH;
    f32x4 ac0 = {0,0,0,0}, ac1 = {0,0,0,0}, ac2 = {0,0,0,0}, ac3 = {0,0,0,0};

#pragma unroll
    for (int ks = 0; ks < 4; ++ks) {
        int ko = ks * 32 + quad * 8;
        float4 xa = *(const float4*)&xr[ko];
        float4 xb = *(const float4*)&xr[ko + 4];
        bf16x8 a;
        a[0] = (short)f2bf(xa.x); a[1] = (short)f2bf(xa.y);
        a[2] = (short)f2bf(xa.z); a[3] = (short)f2bf(xa.w);
        a[4] = (short)f2bf(xb.x); a[5] = (short)f2bf(xb.y);
        a[6] = (short)f2bf(xb.z); a[7] = (short)f2bf(xb.w);
        bf16x8 b0 = *(const bf16x8*)&Bl[( 0 + l16) * 136 + ko];
        bf16x8 b1 = *(const bf16x8*)&Bl[(16 + l16) * 136 + ko];
        bf16x8 b2 = *(const bf16x8*)&Bl[(32 + l16) * 136 + ko];
        bf16x8 b3 = *(const bf16x8*)&Bl[(48 + l16) * 136 + ko];
        ac0 = __builtin_amdgcn_mfma_f32_16x16x32_bf16(a, b0, ac0, 0, 0, 0);
        ac1 = __builtin_amdgcn_mfma_f32_16x16x32_bf16(a, b1, ac1, 0, 0, 0);
        ac2 = __builtin_amdgcn_mfma_f32_16x16x32_bf16(a, b2, ac2, 0, 0, 0);
        ac3 = __builtin_amdgcn_mfma_f32_16x16x32_bf16(a, b3, ac3, 0, 0, 0);
    }

#pragma unroll
    for (int r = 0; r < 4; ++r) {
        int rl = wave * 16 + quad * 4 + r;
        long long grow = node0 + rl;
        if (grow < N_NODES) {
            float dd = dl[rl];
            h1s[grow * 64 +  0 + l16] = f2bf(ac0[r] * dd);
            h1s[grow * 64 + 16 + l16] = f2bf(ac1[r] * dd);
            h1s[grow * 64 + 32 + l16] = f2bf(ac2[r] * dd);
            h1s[grow * 64 + 48 + l16] = f2bf(ac3[r] * dd);
        } else {   // zero pad rows N..NPAD-1 (incl. the gather no-op row N)
            h1s[grow * 64 +  0 + l16] = 0;
            h1s[grow * 64 + 16 + l16] = 0;
            h1s[grow * 64 + 32 + l16] = 0;
            h1s[grow * 64 + 48 + l16] = 0;
        }
    }
}

// ---------------------------------------------------------------------------
// FUSED agg1 + gemm2, PAIR-GATHER + 2x SOFTWARE PIPELINE: 32 nodes/block;
// a 16-lane group owns TWO nodes (8-lane halves); each half loads bf16x8
// (full 128-B row per 8 lanes). The gather loop is unrolled x2 with BOTH
// index loads and ALL 16 row gathers issued before any accumulate — doubles
// cache lines in flight per wave (round-7's +8% came from the first doubling
// via bytes/instr; this stacks the second via instrs outstanding).
// Phase C: 32x48 MFMA tile on waves 0-1.
// ---------------------------------------------------------------------------
__global__ __launch_bounds__(256, 4)
void k_agg1g2(const int* __restrict__ row_start, const int* __restrict__ row_end,
              const int* __restrict__ csr_src,
              const unsigned short* __restrict__ h1s, const float* __restrict__ dinv,
              const float* __restrict__ b1, const float* __restrict__ W2,
              unsigned short* __restrict__ h2s) {
    __shared__ unsigned short Al[32 * 72];  // 4.5 KB relu'd layer-2 input tile
    __shared__ unsigned short Bl[48 * 72];  // 6.75 KB W2^T bf16, n>=40 zero
    __shared__ float dl[32];
    int tid = threadIdx.x;
    long long node0 = (long long)blockIdx.x * 32;

    // stage W2^T (+pad) from fp32 [64][40]
    for (int i = tid; i < 48 * 64; i += 256) {
        int nn = i >> 6, k = i & 63;
        Bl[nn * 72 + k] = f2bf(nn < OUT_CH ? W2[k * OUT_CH + nn] : 0.0f);
    }
    if (tid < 32) {
        long long gr = node0 + tid;
        dl[tid] = dinv[gr < N_NODES ? gr : N_NODES - 1];
    }
    __syncthreads();   // dl needed below

    int g  = tid >> 4;          // group 0..15 (2 nodes each)
    int hh = (tid >> 3) & 1;    // half 0/1 within group
    int c8 = tid & 7;           // lane within half: channel slice [c8*8, c8*8+8)
    int nl = g * 2 + hh;        // local node 0..31
    long long node = node0 + nl;

    int e0 = 0, d = 0;
    if (node < N_NODES) { e0 = row_start[node]; d = row_end[node] - e0; }
    int len8 = (d + 7) & ~7;                       // padded length (mult of 8)
    int lenO = __shfl_xor(len8, 8, 16);            // other half's length
    int nIt  = (len8 > lenO ? len8 : lenO) >> 3;   // group-uniform iterations

    // 4 accumulators (A/B phases) x 8 channels
    float4 aA = {0.f,0.f,0.f,0.f}, aB = aA, aC = aA, aD = aA;
    const unsigned short* Hc = h1s + (long long)c8 * 8;

#define SHFL8(IDX, V0,V1,V2,V3,V4,V5,V6,V7, REAL) \
    int V0=__shfl(IDX,0,8), V1=__shfl(IDX,1,8), V2=__shfl(IDX,2,8), \
        V3=__shfl(IDX,3,8), V4=__shfl(IDX,4,8), V5=__shfl(IDX,5,8), \
        V6=__shfl(IDX,6,8), V7=__shfl(IDX,7,8); \
    if (!REAL) { V0=V1=V2=V3=V4=V5=V6=V7=N_NODES; }
#define GATH8(R, S0,S1,S2,S3,S4,S5,S6,S7) \
    bf16x8 R##0 = *(const bf16x8*)&Hc[(long long)S0 * 64]; \
    bf16x8 R##1 = *(const bf16x8*)&Hc[(long long)S1 * 64]; \
    bf16x8 R##2 = *(const bf16x8*)&Hc[(long long)S2 * 64]; \
    bf16x8 R##3 = *(const bf16x8*)&Hc[(long long)S3 * 64]; \
    bf16x8 R##4 = *(const bf16x8*)&Hc[(long long)S4 * 64]; \
    bf16x8 R##5 = *(const bf16x8*)&Hc[(long long)S5 * 64]; \
    bf16x8 R##6 = *(const bf16x8*)&Hc[(long long)S6 * 64]; \
    bf16x8 R##7 = *(const bf16x8*)&Hc[(long long)S7 * 64];
#define ACC8(R, LO, HI) { \
    LO.x += bf2f((unsigned short)R[0]); LO.y += bf2f((unsigned short)R[1]); \
    LO.z += bf2f((unsigned short)R[2]); LO.w += bf2f((unsigned short)R[3]); \
    HI.x += bf2f((unsigned short)R[4]); HI.y += bf2f((unsigned short)R[5]); \
    HI.z += bf2f((unsigned short)R[6]); HI.w += bf2f((unsigned short)R[7]); }
#define ACCALL(R) ACC8(R##0, aA, aB) ACC8(R##1, aC, aD) ACC8(R##2, aA, aB) \
                  ACC8(R##3, aC, aD) ACC8(R##4, aA, aB) ACC8(R##5, aC, aD) \
                  ACC8(R##6, aA, aB) ACC8(R##7, aC, aD)

    int it = 0;
    while (it + 2 <= nIt) {
        bool realA = ((it    ) << 3) < len8;
        bool realB = ((it + 1) << 3) < len8;
        int baseA = realA ? (e0 + ((it    ) << 3)) : e0;
        int baseB = realB ? (e0 + ((it + 1) << 3)) : e0;
        int idxA = csr_src[baseA + c8];
        int idxB = csr_src[baseB + c8];
        SHFL8(idxA, pa0,pa1,pa2,pa3,pa4,pa5,pa6,pa7, realA)
        GATH8(rA, pa0,pa1,pa2,pa3,pa4,pa5,pa6,pa7)
        SHFL8(idxB, pb0,pb1,pb2,pb3,pb4,pb5,pb6,pb7, realB)
        GATH8(rB, pb0,pb1,pb2,pb3,pb4,pb5,pb6,pb7)
        ACCALL(rA)
        ACCALL(rB)
        it += 2;
    }
    if (it < nIt) {
        bool realA = (it << 3) < len8;
        int baseA = realA ? (e0 + (it << 3)) : e0;
        int idxA = csr_src[baseA + c8];
        SHFL8(idxA, pa0,pa1,pa2,pa3,pa4,pa5,pa6,pa7, realA)
        GATH8(rA, pa0,pa1,pa2,pa3,pa4,pa5,pa6,pa7)
        ACCALL(rA)
    }
    // combine phase accumulators -> 8 channel sums
    aA.x += aC.x; aA.y += aC.y; aA.z += aC.z; aA.w += aC.w;
    aB.x += aD.x; aB.y += aD.y; aB.z += aD.z; aB.w += aD.w;

    // epilogue: +self, *dinv, +bias, relu -> bf16 Al slice (16-B store)
    bf16x8 res = {0,0,0,0,0,0,0,0};
    if (node < N_NODES) {
        bf16x8 sv = *(const bf16x8*)&h1s[(long long)node * 64 + c8 * 8];
        aA.x += bf2f((unsigned short)sv[0]); aA.y += bf2f((unsigned short)sv[1]);
        aA.z += bf2f((unsigned short)sv[2]); aA.w += bf2f((unsigned short)sv[3]);
        aB.x += bf2f((unsigned short)sv[4]); aB.y += bf2f((unsigned short)sv[5]);
        aB.z += bf2f((unsigned short)sv[6]); aB.w += bf2f((unsigned short)sv[7]);
        float dd = dl[nl];
        float4 blo = ((const float4*)b1)[c8 * 2];
        float4 bhi = ((const float4*)b1)[c8 * 2 + 1];
        res[0] = (short)f2bf(fmaxf(aA.x * dd + blo.x, 0.f));
        res[1] = (short)f2bf(fmaxf(aA.y * dd + blo.y, 0.f));
        res[2] = (short)f2bf(fmaxf(aA.z * dd + blo.z, 0.f));
        res[3] = (short)f2bf(fmaxf(aA.w * dd + blo.w, 0.f));
        res[4] = (short)f2bf(fmaxf(aB.x * dd + bhi.x, 0.f));
        res[5] = (short)f2bf(fmaxf(aB.y * dd + bhi.y, 0.f));
        res[6] = (short)f2bf(fmaxf(aB.z * dd + bhi.z, 0.f));
        res[7] = (short)f2bf(fmaxf(aB.w * dd + bhi.w, 0.f));
    }
    *(bf16x8*)&Al[nl * 72 + c8 * 8] = res;   // byte ofs nl*144 + c8*16: 16-B aligned
    __syncthreads();

    // Phase C: 32x48 MFMA tile (gemm2) on waves 0-1; rows >= N written zero
    int lane = tid & 63, wave = tid >> 6;
    if (wave < 2) {
        int quad = lane >> 4, l16 = lane & 15;
        int arow = wave * 16 + l16;
        f32x4 ac0 = {0,0,0,0}, ac1 = {0,0,0,0}, ac2 = {0,0,0,0};

#pragma unroll
        for (int ks = 0; ks < 2; ++ks) {
            int ko = ks * 32 + quad * 8;
            bf16x8 a  = *(const bf16x8*)&Al[arow * 72 + ko];
            bf16x8 b0 = *(const bf16x8*)&Bl[( 0 + l16) * 72 + ko];
            bf16x8 b1v = *(const bf16x8*)&Bl[(16 + l16) * 72 + ko];
            bf16x8 b2 = *(const bf16x8*)&Bl[(32 + l16) * 72 + ko];
            ac0 = __builtin_amdgcn_mfma_f32_16x16x32_bf16(a, b0, ac0, 0, 0, 0);
            ac1 = __builtin_amdgcn_mfma_f32_16x16x32_bf16(a, b1v, ac1, 0, 0, 0);
            ac2 = __builtin_amdgcn_mfma_f32_16x16x32_bf16(a, b2, ac2, 0, 0, 0);
        }

#pragma unroll
        for (int r = 0; r < 4; ++r) {
            int rl = wave * 16 + quad * 4 + r;
            long long grow = node0 + rl;
            if (grow < N_NODES) {
                float dd = dl[rl];
                h2s[grow * 40 +  0 + l16] = f2bf(ac0[r] * dd);
                h2s[grow * 40 + 16 + l16] = f2bf(ac1[r] * dd);
                if (l16 < 8) h2s[grow * 40 + 32 + l16] = f2bf(ac2[r] * dd);
            } else if (grow < NPAD) {   // zero pad rows (gather no-op row N)
                h2s[grow * 40 +  0 + l16] = 0;
                h2s[grow * 40 + 16 + l16] = 0;
                if (l16 < 8) h2s[grow * 40 + 32 + l16] = 0;
            }
        }
    }
#undef SHFL8
#undef GATH8
#undef ACC8
#undef ACCALL
}

// ---------------------------------------------------------------------------
// CSR aggregation layer 2 (+bias), PAIR-GATHER + 2x SOFTWARE PIPELINE:
// same unrolled shape as k_agg1g2; h2s rows PACKED 40ch/80B; lanes c8>=5
// read the hot zero row via zero row-multiplier. fp32 float4 epilogue.
// ---------------------------------------------------------------------------
__global__ __launch_bounds__(256, 4)
void k_agg2(const int* __restrict__ row_start, const int* __restrict__ row_end,
            const int* __restrict__ csr_src,
            const unsigned short* __restrict__ h2s, const float* __restrict__ dinv,
            const float* __restrict__ b2, float* __restrict__ out) {
    int tid = threadIdx.x;
    long long node0 = (long long)blockIdx.x * 32;

    int g  = tid >> 4;          // group 0..15 (2 nodes each)
    int hh = (tid >> 3) & 1;    // half 0/1 within group
    int c8 = tid & 7;           // lane within half
    int nl = g * 2 + hh;        // local node 0..31
    long long node = node0 + nl;
    bool act = c8 < 5;          // channels c8*8..c8*8+7 valid for c8<5

    int e0 = 0, d = 0;
    if (node < N_NODES) { e0 = row_start[node]; d = row_end[node] - e0; }
    int len8 = (d + 7) & ~7;
    int lenO = __shfl_xor(len8, 8, 16);
    int nIt  = (len8 > lenO ? len8 : lenO) >> 3;

    // lanes c8>=5: base = zero row, row-multiplier 0 -> always the hot line
    const unsigned short* Hb = h2s + (act ? (long long)c8 * 8
                                          : (long long)N_NODES * 40);
    long long rmul = act ? 40LL : 0LL;

    float4 aA = {0.f,0.f,0.f,0.f}, aB = aA, aC = aA, aD = aA;

#define SHFL8(IDX, V0,V1,V2,V3,V4,V5,V6,V7, REAL) \
    int V0=__shfl(IDX,0,8), V1=__shfl(IDX,1,8), V2=__shfl(IDX,2,8), \
        V3=__shfl(IDX,3,8), V4=__shfl(IDX,4,8), V5=__shfl(IDX,5,8), \
        V6=__shfl(IDX,6,8), V7=__shfl(IDX,7,8); \
    if (!REAL) { V0=V1=V2=V3=V4=V5=V6=V7=N_NODES; }
#define GATH8(R, S0,S1,S2,S3,S4,S5,S6,S7) \
    bf16x8 R##0 = *(const bf16x8*)&Hb[(long long)S0 * rmul]; \
    bf16x8 R##1 = *(const bf16x8*)&Hb[(long long)S1 * rmul]; \
    bf16x8 R##2 = *(const bf16x8*)&Hb[(long long)S2 * rmul]; \
    bf16x8 R##3 = *(const bf16x8*)&Hb[(long long)S3 * rmul]; \
    bf16x8 R##4 = *(const bf16x8*)&Hb[(long long)S4 * rmul]; \
    bf16x8 R##5 = *(const bf16x8*)&Hb[(long long)S5 * rmul]; \
    bf16x8 R##6 = *(const bf16x8*)&Hb[(long long)S6 * rmul]; \
    bf16x8 R##7 = *(const bf16x8*)&Hb[(long long)S7 * rmul];
#define ACC8(R, LO, HI) { \
    LO.x += bf2f((unsigned short)R[0]); LO.y += bf2f((unsigned short)R[1]); \
    LO.z += bf2f((unsigned short)R[2]); LO.w += bf2f((unsigned short)R[3]); \
    HI.x += bf2f((unsigned short)R[4]); HI.y += bf2f((unsigned short)R[5]); \
    HI.z += bf2f((unsigned short)R[6]); HI.w += bf2f((unsigned short)R[7]); }
#define ACCALL(R) ACC8(R##0, aA, aB) ACC8(R##1, aC, aD) ACC8(R##2, aA, aB) \
                  ACC8(R##3, aC, aD) ACC8(R##4, aA, aB) ACC8(R##5, aC, aD) \
                  ACC8(R##6, aA, aB) ACC8(R##7, aC, aD)

    int it = 0;
    while (it + 2 <= nIt) {
        bool realA = ((it    ) << 3) < len8;
        bool realB = ((it + 1) << 3) < len8;
        int baseA = realA ? (e0 + ((it    ) << 3)) : e0;
        int baseB = realB ? (e0 + ((it + 1) << 3)) : e0;
        int idxA = csr_src[baseA + c8];
        int idxB = csr_src[baseB + c8];
        SHFL8(idxA, pa0,pa1,pa2,pa3,pa4,pa5,pa6,pa7, realA)
        GATH8(rA, pa0,pa1,pa2,pa3,pa4,pa5,pa6,pa7)
        SHFL8(idxB, pb0,pb1,pb2,pb3,pb4,pb5,pb6,pb7, realB)
        GATH8(rB, pb0,pb1,pb2,pb3,pb4,pb5,pb6,pb7)
        ACCALL(rA)
        ACCALL(rB)
        it += 2;
    }
    if (it < nIt) {
        bool realA = (it << 3) < len8;
        int baseA = realA ? (e0 + (it << 3)) : e0;
        int idxA = csr_src[baseA + c8];
        SHFL8(idxA, pa0,pa1,pa2,pa3,pa4,pa5,pa6,pa7, realA)
        GATH8(rA, pa0,pa1,pa2,pa3,pa4,pa5,pa6,pa7)
        ACCALL(rA)
    }
    aA.x += aC.x; aA.y += aC.y; aA.z += aC.z; aA.w += aC.w;
    aB.x += aD.x; aB.y += aD.y; aB.z += aD.z; aB.w += aD.w;

    // epilogue: +self, *dinv, +bias -> fp32 out (two float4 stores / lane)
    if (node < N_NODES && act) {
        bf16x8 sv = *(const bf16x8*)&h2s[(long long)node * 40 + c8 * 8];
        aA.x += bf2f((unsigned short)sv[0]); aA.y += bf2f((unsigned short)sv[1]);
        aA.z += bf2f((unsigned short)sv[2]); aA.w += bf2f((unsigned short)sv[3]);
        aB.x += bf2f((unsigned short)sv[4]); aB.y += bf2f((unsigned short)sv[5]);
        aB.z += bf2f((unsigned short)sv[6]); aB.w += bf2f((unsigned short)sv[7]);
        float dd = dinv[node];
        float4 blo = ((const float4*)b2)[c8 * 2];
        float4 bhi = ((const float4*)b2)[c8 * 2 + 1];
        float4 o0, o1;
        o0.x = aA.x * dd + blo.x; o0.y = aA.y * dd + blo.y;
        o0.z = aA.z * dd + blo.z; o0.w = aA.w * dd + blo.w;
        o1.x = aB.x * dd + bhi.x; o1.y = aB.y * dd + bhi.y;
        o1.z = aB.z * dd + bhi.z; o1.w = aB.w * dd + bhi.w;
        float* op = out + node * 40 + c8 * 8;
        *(float4*)op = o0;
        *(float4*)(op + 4) = o1;
    }
#undef SHFL8
#undef GATH8
#undef ACC8
#undef ACCALL
}

// ---------------------------------------------------------------------------
// launch
// ---------------------------------------------------------------------------
extern "C" void kernel_launch(void* const* d_in, const int* in_sizes, int n_in,
                              void* d_out, int out_size, void* d_ws, size_t ws_size,
                              hipStream_t stream) {
    const float* x  = (const float*)d_in[0];
    const int*   ei = (const int*)d_in[1];
    const float* W1 = (const float*)d_in[2];
    const float* b1 = (const float*)d_in[3];
    const float* W2 = (const float*)d_in[4];
    const float* b2 = (const float*)d_in[5];
    float* out = (float*)d_out;

    // workspace layout (16B-aligned regions), ~39 MB:
    // hbuf bf16[64*NPAD] | h2buf bf16[40*NPAD] | ebuf[NBKT*CAP] |
    // csr_src[NBKT*CAPC + 64 slack] | row_start[N] | row_end[N] | gcur[256] | dinv[N]
    unsigned short* hbuf  = (unsigned short*)d_ws;                // 64*NPAD bf16
    unsigned short* h2buf = hbuf + 64LL * NPAD;                   // 40*NPAD bf16
    int* ebuf      = (int*)(h2buf + 40LL * NPAD);                 // NBKT*CAP
    int* csr_src   = ebuf + NBKT * CAP;                           // NBKT*CAPC
    int* row_start = csr_src + NBKT * CAPC + 64;                  // N  (+64 overread slack)
    int* row_end   = row_start + N_NODES;                         // N
    int* gcur      = row_end + N_NODES;                           // 256
    float* dinv    = (float*)(gcur + 256);                        // N

    const int B = 256;
    const int gRows = NPAD / 64;                  // 1563
    const int gAgg  = NPAD / 32;                  // 3126

    hipMemsetAsync((void*)gcur, 0, NBKT * sizeof(int), stream);
    k_bin<<<(N_EDGES + EPB - 1) / EPB, B, 0, stream>>>(ei, gcur, ebuf);
    k_node<<<NBKT, 512, 0, stream>>>(gcur, ebuf, row_start, row_end, csr_src, dinv);

    k_gemm1<<<gRows, B, 0, stream>>>(x, W1, dinv, hbuf);
    k_agg1g2<<<gAgg, B, 0, stream>>>(row_start, row_end, csr_src, hbuf, dinv,
                                     b1, W2, h2buf);
    k_agg2<<<gAgg, B, 0, stream>>>(row_start, row_end, csr_src, h2buf, dinv, b2, out);
}